// Round 11
// baseline (190.387 us; speedup 1.0000x reference)
//
#include <hip/hip_runtime.h>
#include <math.h>

#define LRES 1024
#define TOPK 48
#define NEDGE (LRES*TOPK)

typedef short short8 __attribute__((ext_vector_type(8)));
typedef float f32x4  __attribute__((ext_vector_type(4)));

// ---- output layout (floats). Tuple concat: E, E_idx, E_s, E_idx_sub ----
#define OUT_E     0
#define OUT_EIDX  6291456          // 1024*48*128
#define OUT_ES    6340608          // + 49152
#define OUT_EIDX2 12632064         // + 6291456

// ---- workspace layout (float offsets) ----
#define WS_COORDS 0                // 1024*15 floats
#define WS_DNB    15360            // 49152 floats
#define WS_EIDX   64512            // 49152 ints
#define WS_WPE    113664           // 53248 shorts: W_e packed B-frags
#define WS_WPS    140288           // 163840 shorts: W_s packed B-frags

// RBF recurrence constants.
// edgeE: mu = 2 + r*(4/3), invsig = 0.8  -> u=(d-2)*0.8, Delta = 16/15
#define DE 1.06666667f
#define QE 0.10273976f             // exp(-2*DE^2)
// edgeS: mu = 2 + r*(20/7), invsig = 0.4 -> u=(d-2)*0.4, Delta = 8/7
#define DS 1.14285714f
#define QS 0.07337053f             // exp(-2*DS^2)

// pair -> anchor index maps (N=0, Ca=1, C=2, O=3, Cb=4)
__constant__ int PA[24] = {0,2,3,4,1,1,1,1,0,0,0,4,4,3,0,2,3,4,2,3,4,2,3,2};
__constant__ int PB[24] = {0,2,3,4,0,2,3,4,2,3,4,2,3,2,1,1,1,1,0,0,0,4,4,3};

__device__ inline short f2bf(float f) {           // RNE, off hot path (weights)
    unsigned u = __float_as_uint(f);
    unsigned r = (u + 0x7FFFu + ((u >> 16) & 1u)) >> 16;
    return (short)r;
}

// pack 8 floats -> short8 bf16 by truncation: 1 v_perm per 2 values
__device__ inline short8 pack8(const float* fv) {
    union { short8 s; unsigned u[4]; } r;
    #pragma unroll
    for (int i = 0; i < 4; ++i)
        r.u[i] = __builtin_amdgcn_perm(__float_as_uint(fv[2*i+1]),
                                       __float_as_uint(fv[2*i]), 0x07060302u);
    return r.s;
}

// K-split reduction + LayerNorm + NT store, constant-time epilogue (r7-proven).
// Waves write DISJOINT hb regions; thread (e,c) sums the 4 partials for its 8
// columns, butterfly-reduces LN stats within its 16-thread group, stores from
// registers. NT: outputs never re-read; keeps write stream from evicting L2.
template<int MT>
__device__ __forceinline__ void kred_ln(const f32x4 (*acc)[8], float* hb,
                                        float* outp, const float* g,
                                        const float* b, int t, int w,
                                        int quad, int l16) {
    int e = t >> 4, c = t & 15;
    float gv[8], bv[8];
    #pragma unroll
    for (int k = 0; k < 8; ++k) { gv[k] = g[c + 16*k]; bv[k] = b[c + 16*k]; }
    float* hw = hb + w*2144;
    #pragma unroll
    for (int mt = 0; mt < MT; ++mt) {
        __syncthreads();                       // hb free (K-loop / prev pass done)
        #pragma unroll
        for (int nt = 0; nt < 8; ++nt)
        #pragma unroll
        for (int r = 0; r < 4; ++r)
            hw[(quad*4 + r)*134 + nt*16 + l16] = acc[mt][nt][r];
        __syncthreads();
        float s = 0.f, s2 = 0.f, vals[8];
        #pragma unroll
        for (int k = 0; k < 8; ++k) {
            int col = e*134 + c + 16*k;
            float v = hb[col] + hb[2144 + col] + hb[4288 + col] + hb[6432 + col];
            vals[k] = v; s += v; s2 = fmaf(v, v, s2);
        }
        #pragma unroll
        for (int m = 1; m <= 8; m <<= 1) {
            s  += __shfl_xor(s,  m);
            s2 += __shfl_xor(s2, m);
        }
        float mu = s * 0.0078125f;
        float rs = rsqrtf(fmaf(s2, 0.0078125f, -mu*mu) + 1e-5f);
        float* row = outp + (size_t)(mt*16 + e)*128 + c;
        #pragma unroll
        for (int k = 0; k < 8; ++k)
            __builtin_nontemporal_store(gv[k]*(vals[k] - mu)*rs + bv[k],
                                        &row[16*k]);
    }
}

// ============ K_PRE: topk (blocks 0..255) | pack (256..895) | coords (896..899) =====
__global__ __launch_bounds__(256) void k_pre(const float* __restrict__ X,
                                             const float* __restrict__ mask,
                                             const float* __restrict__ We,
                                             const float* __restrict__ Ws,
                                             float* __restrict__ coords,
                                             short* __restrict__ WpE,
                                             short* __restrict__ WpS,
                                             float* __restrict__ Dnb,
                                             int* __restrict__ Eidx,
                                             float* __restrict__ out) {
    int blk = blockIdx.x, t = threadIdx.x;
    if (blk < 256) {
        // ---------------- top-48 per row, one wave per row ----------------
        __shared__ float sCa[LRES*3];
        __shared__ float sM[LRES];
        for (int j = t; j < LRES; j += 256) {
            sCa[j*3+0] = X[j*111 + 3];
            sCa[j*3+1] = X[j*111 + 4];
            sCa[j*3+2] = X[j*111 + 5];
            sM[j] = mask[j];
        }
        __syncthreads();
        int w = t >> 6, lane = t & 63;
        int i = blk * 4 + w;
        float cx = sCa[i*3], cy = sCa[i*3+1], cz = sCa[i*3+2];
        float mi = sM[i];
        float dv[16], m2v[16];
        float lmax = -1e30f;
        #pragma unroll
        for (int s = 0; s < 16; ++s) {
            int j = s*64 + lane;
            float dx = cx - sCa[j*3], dy = cy - sCa[j*3+1], dz = cz - sCa[j*3+2];
            float d  = __builtin_amdgcn_sqrtf(dx*dx + dy*dy + dz*dz + 1e-6f);
            float m2 = mi * sM[j];
            dv[s] = m2 * d; m2v[s] = m2;
            lmax = fmaxf(lmax, dv[s]);
        }
        #pragma unroll
        for (int off = 32; off; off >>= 1) lmax = fmaxf(lmax, __shfl_xor(lmax, off));
        unsigned long long key[16];
        unsigned long long mkey = ~0ull; int mslot = 0;
        #pragma unroll
        for (int s = 0; s < 16; ++s) {
            float dadj = dv[s] + (1.0f - m2v[s]) * lmax;
            key[s] = (((unsigned long long)__float_as_uint(dadj)) << 10) | (unsigned)(s*64 + lane);
            if (key[s] < mkey) { mkey = key[s]; mslot = s; }
        }
        for (int it = 0; it < TOPK; ++it) {
            unsigned long long wk = mkey;
            #pragma unroll
            for (int off = 32; off; off >>= 1) {
                unsigned long long o = __shfl_xor(wk, off);
                wk = (o < wk) ? o : wk;
            }
            if (lane == 0) {
                int j = (int)(wk & 1023u);
                int id = i*TOPK + it;
                Dnb[id]  = __uint_as_float((unsigned)(wk >> 10));
                Eidx[id] = j;
                out[OUT_EIDX  + id] = (float)j;
                out[OUT_EIDX2 + id] = (float)j;
            }
            if (mkey == wk) {
                key[mslot] = ~0ull;
                mkey = ~0ull;
                #pragma unroll
                for (int s = 0; s < 16; ++s)
                    if (key[s] < mkey) { mkey = key[s]; mslot = s; }
            }
        }
    } else if (blk < 896) {
        // ---------------- pack W_e / W_s into MFMA B-fragment order ----------------
        int g = (blk - 256) * 256 + t;
        if (g < 8*13*64*8) {
            int j = g & 7, lane = (g >> 3) & 63, gg = g >> 9;
            int ks = gg % 13, nt = gg / 13;
            int n = nt*16 + (lane & 15), k = ks*32 + (lane >> 4)*8 + j;
            WpE[g] = f2bf(We[n*416 + k]);
        }
        if (g < 8*40*64*8) {
            int j = g & 7, lane = (g >> 3) & 63, gg = g >> 9;
            int ks = gg % 40, nt = gg / 40;
            int n = nt*16 + (lane & 15), k = ks*32 + (lane >> 4)*8 + j;
            WpS[g] = f2bf(Ws[n*1280 + k]);
        }
    } else {
        // ---------------- per-residue coords N,Ca,C,O,Cb ----------------
        int r = (blk - 896) * 256 + t;
        if (r >= LRES) return;
        const float* xr = X + r * 111;
        float N[3], Ca[3], C[3], O[3], bv[3], cv[3], av[3];
        #pragma unroll
        for (int d = 0; d < 3; ++d) {
            N[d]  = xr[0*3 + d];  Ca[d] = xr[1*3 + d];
            C[d]  = xr[2*3 + d];  O[d]  = xr[4*3 + d];
            bv[d] = Ca[d] - N[d]; cv[d] = C[d] - Ca[d];
        }
        av[0] = bv[1]*cv[2] - bv[2]*cv[1];
        av[1] = bv[2]*cv[0] - bv[0]*cv[2];
        av[2] = bv[0]*cv[1] - bv[1]*cv[0];
        float* o = coords + r * 15;
        #pragma unroll
        for (int d = 0; d < 3; ++d) {
            float Cb = -0.58273431f*av[d] + 0.56802827f*bv[d] - 0.54067466f*cv[d] + Ca[d];
            o[0*3+d] = N[d]; o[1*3+d] = Ca[d]; o[2*3+d] = C[d];
            o[3*3+d] = O[d]; o[4*3+d] = Cb;
        }
    }
}

// ============ K_EDGE: edgeS (blocks 0..767) | edgeE (768..1535) ============
// r9 structure (session best): 64 edges/block, mt=4, 4 waves, K-split across
// waves, per-wave direct B-reads from L2 (weights L2-resident; each B-frag
// feeds 4 MFMAs). No in-loop barriers -> waves drift to different phases;
// s_setprio(1) around the MFMA burst (T5) lets the CU scheduler favor the
// MFMA-entering wave over load-issuing waves. Constant-time epilogue
// (kred_ln), NT stores.
__global__ __launch_bounds__(256, 2) void k_edge(const float* __restrict__ coords,
                                                 const float* __restrict__ X,
                                                 const float* __restrict__ amask,
                                                 const short* __restrict__ WpE,
                                                 const short* __restrict__ WpS,
                                                 const float* __restrict__ Dnb,
                                                 const int* __restrict__ Eidx,
                                                 const int* __restrict__ ri,
                                                 const int* __restrict__ ch,
                                                 const float* __restrict__ Wpos,
                                                 const float* __restrict__ bpos,
                                                 const float* __restrict__ ge,
                                                 const float* __restrict__ be,
                                                 const float* __restrict__ gs,
                                                 const float* __restrict__ bs,
                                                 float* __restrict__ out) {
    __shared__ float smem[8624];
    int t = threadIdx.x;
    int w = t >> 6, lane = t & 63, quad = lane >> 4, l16 = lane & 15;
    float* hb = smem;                          // 4*2144 = 8576: partials buffer

    if (blockIdx.x < 768) {
        // =============== edgeS: 1280 -> 128 matvec + LN ===============
        float* sA3 = smem + 8576;              // 30: 2 rows x 15 (64-edge block
        int id0 = blockIdx.x * 64;             //     spans at most 2 rows)
        int i0 = id0 / TOPK;

        if (t < 30) {
            int rr = i0 + t / 15;
            if (rr > LRES-1) rr = LRES-1;
            sA3[t] = coords[rr*15 + t%15];
        }
        // per-lane register operands
        int s1 = 4*w + quad;                   // sidechain atom for half 0
        float S[4][2][3], am[4][2];
        int im[4];
        #pragma unroll
        for (int mt = 0; mt < 4; ++mt) {
            int id = id0 + mt*16 + l16;
            int j  = Eidx[id];
            im[mt] = id / TOPK;
            const float* xp = X + (j*37 + 5)*3;
            const float* ap = amask + j*37 + 5;
            #pragma unroll
            for (int h = 0; h < 2; ++h) {
                int s = s1 + h*16;
                S[mt][h][0] = xp[s*3+0];
                S[mt][h][1] = xp[s*3+1];
                S[mt][h][2] = xp[s*3+2];
                am[mt][h]   = ap[s];
            }
        }
        __syncthreads();

        f32x4 acc[4][8] = {};
        const short8* bp = (const short8*)WpS;

        for (int a = 0; a < 5; ++a) {
            float A[4][3];
            #pragma unroll
            for (int mt = 0; mt < 4; ++mt) {
                int base = (im[mt] - i0)*15 + a*3;
                A[mt][0] = sA3[base+0];
                A[mt][1] = sA3[base+1];
                A[mt][2] = sA3[base+2];
            }
            #pragma unroll
            for (int h = 0; h < 2; ++h) {
                int ks = a*8 + w + h*4;
                short8 afrag[4];
                #pragma unroll
                for (int mt = 0; mt < 4; ++mt) {
                    float dx = A[mt][0] - S[mt][h][0];
                    float dy = A[mt][1] - S[mt][h][1];
                    float dz = A[mt][2] - S[mt][h][2];
                    float d  = __builtin_amdgcn_sqrtf(fmaf(dz,dz,fmaf(dy,dy,fmaf(dx,dx,1e-6f))));
                    float u  = fmaf(d, 0.4f, -0.8f);
                    float e0 = __expf(-u*u) * am[mt][h];
                    float g  = __expf(fmaf(2.0f*DS, u, -DS*DS));
                    float fv[8];
                    fv[0] = e0;
                    #pragma unroll
                    for (int r = 1; r < 8; ++r) { e0 *= g; g *= QS; fv[r] = e0; }
                    afrag[mt] = pack8(fv);
                }
                __builtin_amdgcn_s_setprio(1);
                #pragma unroll
                for (int nt = 0; nt < 8; ++nt) {
                    short8 b = bp[(nt*40 + ks)*64 + lane];
                    acc[0][nt] = __builtin_amdgcn_mfma_f32_16x16x32_bf16(afrag[0], b, acc[0][nt], 0,0,0);
                    acc[1][nt] = __builtin_amdgcn_mfma_f32_16x16x32_bf16(afrag[1], b, acc[1][nt], 0,0,0);
                    acc[2][nt] = __builtin_amdgcn_mfma_f32_16x16x32_bf16(afrag[2], b, acc[2][nt], 0,0,0);
                    acc[3][nt] = __builtin_amdgcn_mfma_f32_16x16x32_bf16(afrag[3], b, acc[3][nt], 0,0,0);
                }
                __builtin_amdgcn_s_setprio(0);
            }
        }
        kred_ln<4>(acc, hb, out + OUT_ES + (size_t)id0*128, gs, bs, t, w, quad, l16);
    } else {
        // =============== edgeE: 416 -> 128 matvec + LN ===============
        // Scratch aliased inside hb: sdist/sposf are read through the K-loop,
        // which all waves finish before kred_ln's first barrier overwrites hb.
        float* sdist = hb;                     // 1728 (64 x 27): [0]=Dnb, [1+p]
        float* sposf = hb + 1728;              // 1088 (64 x 17)
        int*   sdpos = (int*)(hb + 2816);      // 64
        float* sA    = hb + 2880;              // 960 (64 x 15, dead after precompute)
        float* sB    = hb + 3840;              // 960 (64 x 15, dead after precompute)
        int id0 = (blockIdx.x - 768) * 64;

        if (t < 64) {
            int id = id0 + t, i = id / TOPK, j = Eidx[id];
            int off = ri[i] - ri[j];
            sdpos[t] = (ch[i] == ch[j]) ? min(max(off + 32, 0), 64) : 65;
            sdist[t*27] = Dnb[id];
        }
        for (int it = t; it < 64*15; it += 256) {
            int e = it / 15, q = it % 15;
            int id = id0 + e, i = id / TOPK, j = Eidx[id];
            sA[e*15+q] = coords[i*15+q];
            sB[e*15+q] = coords[j*15+q];
        }
        __syncthreads();
        for (int it = t; it < 64*24; it += 256) {
            int e = it / 24, p = it % 24, a = PA[p], b = PB[p];
            float dx = sA[e*15+a*3+0] - sB[e*15+b*3+0];
            float dy = sA[e*15+a*3+1] - sB[e*15+b*3+1];
            float dz = sA[e*15+a*3+2] - sB[e*15+b*3+2];
            sdist[e*27 + 1 + p] = __builtin_amdgcn_sqrtf(dx*dx + dy*dy + dz*dz + 1e-6f);
        }
        for (int it = t; it < 64*16; it += 256) {
            int e = it >> 4, c = it & 15;
            sposf[e*17 + c] = Wpos[c*66 + sdpos[e]] + bpos[c];
        }
        __syncthreads();

        f32x4 acc[4][8] = {};
        const short8* bp = (const short8*)WpE;
        float rb = (quad & 1) ? 8.0f*DE : 0.0f;

        for (int ks = w; ks < 13; ks += 4) {
            short8 afrag[4];
            #pragma unroll
            for (int mt = 0; mt < 4; ++mt) {
                int e = mt*16 + l16;
                float fv[8];
                if (ks == 0 && quad < 2) {
                    #pragma unroll
                    for (int j = 0; j < 8; ++j) fv[j] = sposf[e*17 + quad*8 + j];
                } else {
                    int p = (ks == 0) ? 0 : (2*ks - 1 + (quad >> 1));
                    float d = sdist[e*27 + p];
                    float u = fmaf(d, 0.8f, -1.6f) - rb;
                    float e0 = __expf(-u*u);
                    float g  = __expf(fmaf(2.0f*DE, u, -DE*DE));
                    fv[0] = e0;
                    #pragma unroll
                    for (int r = 1; r < 8; ++r) { e0 *= g; g *= QE; fv[r] = e0; }
                }
                afrag[mt] = pack8(fv);
            }
            __builtin_amdgcn_s_setprio(1);
            #pragma unroll
            for (int nt = 0; nt < 8; ++nt) {
                short8 b = bp[(nt*13 + ks)*64 + lane];
                acc[0][nt] = __builtin_amdgcn_mfma_f32_16x16x32_bf16(afrag[0], b, acc[0][nt], 0,0,0);
                acc[1][nt] = __builtin_amdgcn_mfma_f32_16x16x32_bf16(afrag[1], b, acc[1][nt], 0,0,0);
                acc[2][nt] = __builtin_amdgcn_mfma_f32_16x16x32_bf16(afrag[2], b, acc[2][nt], 0,0,0);
                acc[3][nt] = __builtin_amdgcn_mfma_f32_16x16x32_bf16(afrag[3], b, acc[3][nt], 0,0,0);
            }
            __builtin_amdgcn_s_setprio(0);
        }
        kred_ln<4>(acc, hb, out + OUT_E + (size_t)id0*128, ge, be, t, w, quad, l16);
    }
}

extern "C" void kernel_launch(void* const* d_in, const int* in_sizes, int n_in,
                              void* d_out, int out_size, void* d_ws, size_t ws_size,
                              hipStream_t stream) {
    (void)in_sizes; (void)n_in; (void)out_size; (void)ws_size;
    const float* X     = (const float*)d_in[0];
    const float* mask  = (const float*)d_in[2];
    const float* amask = (const float*)d_in[3];
    const int*   ri    = (const int*)d_in[4];
    const int*   ch    = (const int*)d_in[6];
    const float* Wpos  = (const float*)d_in[7];
    const float* bpos  = (const float*)d_in[8];
    const float* We    = (const float*)d_in[9];
    const float* ge    = (const float*)d_in[10];
    const float* be    = (const float*)d_in[11];
    const float* Ws    = (const float*)d_in[12];
    const float* gs    = (const float*)d_in[13];
    const float* bs    = (const float*)d_in[14];

    float* out    = (float*)d_out;
    float* ws     = (float*)d_ws;
    float* coords = ws + WS_COORDS;
    float* Dnb    = ws + WS_DNB;
    int*   Eidx   = (int*)(ws + WS_EIDX);
    short* WpE    = (short*)(ws + WS_WPE);
    short* WpS    = (short*)(ws + WS_WPS);

    k_pre <<<dim3(900),  dim3(256), 0, stream>>>(X, mask, We, Ws, coords,
                                                 WpE, WpS, Dnb, Eidx, out);
    k_edge<<<dim3(1536), dim3(256), 0, stream>>>(coords, X, amask, WpE, WpS,
                                                 Dnb, Eidx, ri, ch, Wpos, bpos,
                                                 ge, be, gs, bs, out);
}

// Round 12
// 181.599 us; speedup vs baseline: 1.0484x; 1.0484x over previous
//
#include <hip/hip_runtime.h>
#include <math.h>

#define LRES 1024
#define TOPK 48
#define NEDGE (LRES*TOPK)

typedef short short8 __attribute__((ext_vector_type(8)));
typedef float f32x4  __attribute__((ext_vector_type(4)));

// ---- output layout (floats). Tuple concat: E, E_idx, E_s, E_idx_sub ----
#define OUT_E     0
#define OUT_EIDX  6291456          // 1024*48*128
#define OUT_ES    6340608          // + 49152
#define OUT_EIDX2 12632064         // + 6291456

// ---- workspace layout (float offsets) ----
#define WS_COORDS 0                // 1024*15 floats
#define WS_DNB    15360            // 49152 floats
#define WS_EIDX   64512            // 49152 ints
#define WS_WPE    113664           // 53248 shorts: W_e packed B-frags
#define WS_WPS    140288           // 163840 shorts: W_s packed B-frags

// RBF recurrence constants.
// edgeE: mu = 2 + r*(4/3), invsig = 0.8  -> u=(d-2)*0.8, Delta = 16/15
#define DE 1.06666667f
#define QE 0.10273976f             // exp(-2*DE^2)
// edgeS: mu = 2 + r*(20/7), invsig = 0.4 -> u=(d-2)*0.4, Delta = 8/7
#define DS 1.14285714f
#define QS 0.07337053f             // exp(-2*DS^2)

// pair -> anchor index maps (N=0, Ca=1, C=2, O=3, Cb=4)
__constant__ int PA[24] = {0,2,3,4,1,1,1,1,0,0,0,4,4,3,0,2,3,4,2,3,4,2,3,2};
__constant__ int PB[24] = {0,2,3,4,0,2,3,4,2,3,4,2,3,2,1,1,1,1,0,0,0,4,4,3};

__device__ inline short f2bf(float f) {           // RNE, off hot path (weights)
    unsigned u = __float_as_uint(f);
    unsigned r = (u + 0x7FFFu + ((u >> 16) & 1u)) >> 16;
    return (short)r;
}

// pack 8 floats -> short8 bf16 by truncation: 1 v_perm per 2 values
__device__ inline short8 pack8(const float* fv) {
    union { short8 s; unsigned u[4]; } r;
    #pragma unroll
    for (int i = 0; i < 4; ++i)
        r.u[i] = __builtin_amdgcn_perm(__float_as_uint(fv[2*i+1]),
                                       __float_as_uint(fv[2*i]), 0x07060302u);
    return r.s;
}

// K-split reduction + LayerNorm + NT store, constant-time epilogue (r7-proven).
// Waves write DISJOINT hb regions; thread (e,c) sums the 4 partials for its 8
// columns, butterfly-reduces LN stats within its 16-thread group, stores from
// registers. NT: outputs never re-read; keeps write stream from evicting L2.
template<int MT>
__device__ __forceinline__ void kred_ln(const f32x4 (*acc)[8], float* hb,
                                        float* outp, const float* g,
                                        const float* b, int t, int w,
                                        int quad, int l16) {
    int e = t >> 4, c = t & 15;
    float gv[8], bv[8];
    #pragma unroll
    for (int k = 0; k < 8; ++k) { gv[k] = g[c + 16*k]; bv[k] = b[c + 16*k]; }
    float* hw = hb + w*2144;
    #pragma unroll
    for (int mt = 0; mt < MT; ++mt) {
        __syncthreads();                       // hb free (K-loop / prev pass done)
        #pragma unroll
        for (int nt = 0; nt < 8; ++nt)
        #pragma unroll
        for (int r = 0; r < 4; ++r)
            hw[(quad*4 + r)*134 + nt*16 + l16] = acc[mt][nt][r];
        __syncthreads();
        float s = 0.f, s2 = 0.f, vals[8];
        #pragma unroll
        for (int k = 0; k < 8; ++k) {
            int col = e*134 + c + 16*k;
            float v = hb[col] + hb[2144 + col] + hb[4288 + col] + hb[6432 + col];
            vals[k] = v; s += v; s2 = fmaf(v, v, s2);
        }
        #pragma unroll
        for (int m = 1; m <= 8; m <<= 1) {
            s  += __shfl_xor(s,  m);
            s2 += __shfl_xor(s2, m);
        }
        float mu = s * 0.0078125f;
        float rs = rsqrtf(fmaf(s2, 0.0078125f, -mu*mu) + 1e-5f);
        float* row = outp + (size_t)(mt*16 + e)*128 + c;
        #pragma unroll
        for (int k = 0; k < 8; ++k)
            __builtin_nontemporal_store(gv[k]*(vals[k] - mu)*rs + bv[k],
                                        &row[16*k]);
    }
}

// ============ K_PRE: topk (blocks 0..255) | pack (256..895) | coords (896..899) =====
__global__ __launch_bounds__(256) void k_pre(const float* __restrict__ X,
                                             const float* __restrict__ mask,
                                             const float* __restrict__ We,
                                             const float* __restrict__ Ws,
                                             float* __restrict__ coords,
                                             short* __restrict__ WpE,
                                             short* __restrict__ WpS,
                                             float* __restrict__ Dnb,
                                             int* __restrict__ Eidx,
                                             float* __restrict__ out) {
    int blk = blockIdx.x, t = threadIdx.x;
    if (blk < 256) {
        // ---------------- top-48 per row, one wave per row ----------------
        __shared__ float sCa[LRES*3];
        __shared__ float sM[LRES];
        for (int j = t; j < LRES; j += 256) {
            sCa[j*3+0] = X[j*111 + 3];
            sCa[j*3+1] = X[j*111 + 4];
            sCa[j*3+2] = X[j*111 + 5];
            sM[j] = mask[j];
        }
        __syncthreads();
        int w = t >> 6, lane = t & 63;
        int i = blk * 4 + w;
        float cx = sCa[i*3], cy = sCa[i*3+1], cz = sCa[i*3+2];
        float mi = sM[i];
        float dv[16], m2v[16];
        float lmax = -1e30f;
        #pragma unroll
        for (int s = 0; s < 16; ++s) {
            int j = s*64 + lane;
            float dx = cx - sCa[j*3], dy = cy - sCa[j*3+1], dz = cz - sCa[j*3+2];
            float d  = __builtin_amdgcn_sqrtf(dx*dx + dy*dy + dz*dz + 1e-6f);
            float m2 = mi * sM[j];
            dv[s] = m2 * d; m2v[s] = m2;
            lmax = fmaxf(lmax, dv[s]);
        }
        #pragma unroll
        for (int off = 32; off; off >>= 1) lmax = fmaxf(lmax, __shfl_xor(lmax, off));
        unsigned long long key[16];
        unsigned long long mkey = ~0ull; int mslot = 0;
        #pragma unroll
        for (int s = 0; s < 16; ++s) {
            float dadj = dv[s] + (1.0f - m2v[s]) * lmax;
            key[s] = (((unsigned long long)__float_as_uint(dadj)) << 10) | (unsigned)(s*64 + lane);
            if (key[s] < mkey) { mkey = key[s]; mslot = s; }
        }
        for (int it = 0; it < TOPK; ++it) {
            unsigned long long wk = mkey;
            #pragma unroll
            for (int off = 32; off; off >>= 1) {
                unsigned long long o = __shfl_xor(wk, off);
                wk = (o < wk) ? o : wk;
            }
            if (lane == 0) {
                int j = (int)(wk & 1023u);
                int id = i*TOPK + it;
                Dnb[id]  = __uint_as_float((unsigned)(wk >> 10));
                Eidx[id] = j;
                out[OUT_EIDX  + id] = (float)j;
                out[OUT_EIDX2 + id] = (float)j;
            }
            if (mkey == wk) {
                key[mslot] = ~0ull;
                mkey = ~0ull;
                #pragma unroll
                for (int s = 0; s < 16; ++s)
                    if (key[s] < mkey) { mkey = key[s]; mslot = s; }
            }
        }
    } else if (blk < 896) {
        // ---------------- pack W_e / W_s into MFMA B-fragment order ----------------
        int g = (blk - 256) * 256 + t;
        if (g < 8*13*64*8) {
            int j = g & 7, lane = (g >> 3) & 63, gg = g >> 9;
            int ks = gg % 13, nt = gg / 13;
            int n = nt*16 + (lane & 15), k = ks*32 + (lane >> 4)*8 + j;
            WpE[g] = f2bf(We[n*416 + k]);
        }
        if (g < 8*40*64*8) {
            int j = g & 7, lane = (g >> 3) & 63, gg = g >> 9;
            int ks = gg % 40, nt = gg / 40;
            int n = nt*16 + (lane & 15), k = ks*32 + (lane >> 4)*8 + j;
            WpS[g] = f2bf(Ws[n*1280 + k]);
        }
    } else {
        // ---------------- per-residue coords N,Ca,C,O,Cb ----------------
        int r = (blk - 896) * 256 + t;
        if (r >= LRES) return;
        const float* xr = X + r * 111;
        float N[3], Ca[3], C[3], O[3], bv[3], cv[3], av[3];
        #pragma unroll
        for (int d = 0; d < 3; ++d) {
            N[d]  = xr[0*3 + d];  Ca[d] = xr[1*3 + d];
            C[d]  = xr[2*3 + d];  O[d]  = xr[4*3 + d];
            bv[d] = Ca[d] - N[d]; cv[d] = C[d] - Ca[d];
        }
        av[0] = bv[1]*cv[2] - bv[2]*cv[1];
        av[1] = bv[2]*cv[0] - bv[0]*cv[2];
        av[2] = bv[0]*cv[1] - bv[1]*cv[0];
        float* o = coords + r * 15;
        #pragma unroll
        for (int d = 0; d < 3; ++d) {
            float Cb = -0.58273431f*av[d] + 0.56802827f*bv[d] - 0.54067466f*cv[d] + Ca[d];
            o[0*3+d] = N[d]; o[1*3+d] = Ca[d]; o[2*3+d] = C[d];
            o[3*3+d] = O[d]; o[4*3+d] = Cb;
        }
    }
}

// ============ K_EDGE: edgeS (blocks 0..767) | edgeE (768..1535) ============
// Session-best structure (round 9): 64 edges/block, mt=4, 4 waves, K-split
// across waves, per-wave direct B-reads from L2 (weights L2-resident; each
// B-fragment read feeds 4 MFMAs). Barrier-free K-loop; constant-time
// epilogue (kred_ln); NT output stores. Measured: k_edge 55.6us,
// absmax 0.0234. NOTE: do not add setprio/sched hints here — r11 measured
// -37% from setprio (B-loads are interleaved with MFMAs; priority starves
// cross-wave overlap, and codegen is hint-fragile: VGPR 128->120).
__global__ __launch_bounds__(256, 2) void k_edge(const float* __restrict__ coords,
                                                 const float* __restrict__ X,
                                                 const float* __restrict__ amask,
                                                 const short* __restrict__ WpE,
                                                 const short* __restrict__ WpS,
                                                 const float* __restrict__ Dnb,
                                                 const int* __restrict__ Eidx,
                                                 const int* __restrict__ ri,
                                                 const int* __restrict__ ch,
                                                 const float* __restrict__ Wpos,
                                                 const float* __restrict__ bpos,
                                                 const float* __restrict__ ge,
                                                 const float* __restrict__ be,
                                                 const float* __restrict__ gs,
                                                 const float* __restrict__ bs,
                                                 float* __restrict__ out) {
    __shared__ float smem[8624];
    int t = threadIdx.x;
    int w = t >> 6, lane = t & 63, quad = lane >> 4, l16 = lane & 15;
    float* hb = smem;                          // 4*2144 = 8576: partials buffer

    if (blockIdx.x < 768) {
        // =============== edgeS: 1280 -> 128 matvec + LN ===============
        float* sA3 = smem + 8576;              // 30: 2 rows x 15 (64-edge block
        int id0 = blockIdx.x * 64;             //     spans at most 2 rows)
        int i0 = id0 / TOPK;

        if (t < 30) {
            int rr = i0 + t / 15;
            if (rr > LRES-1) rr = LRES-1;
            sA3[t] = coords[rr*15 + t%15];
        }
        // per-lane register operands
        int s1 = 4*w + quad;                   // sidechain atom for half 0
        float S[4][2][3], am[4][2];
        int im[4];
        #pragma unroll
        for (int mt = 0; mt < 4; ++mt) {
            int id = id0 + mt*16 + l16;
            int j  = Eidx[id];
            im[mt] = id / TOPK;
            const float* xp = X + (j*37 + 5)*3;
            const float* ap = amask + j*37 + 5;
            #pragma unroll
            for (int h = 0; h < 2; ++h) {
                int s = s1 + h*16;
                S[mt][h][0] = xp[s*3+0];
                S[mt][h][1] = xp[s*3+1];
                S[mt][h][2] = xp[s*3+2];
                am[mt][h]   = ap[s];
            }
        }
        __syncthreads();

        f32x4 acc[4][8] = {};
        const short8* bp = (const short8*)WpS;

        for (int a = 0; a < 5; ++a) {
            float A[4][3];
            #pragma unroll
            for (int mt = 0; mt < 4; ++mt) {
                int base = (im[mt] - i0)*15 + a*3;
                A[mt][0] = sA3[base+0];
                A[mt][1] = sA3[base+1];
                A[mt][2] = sA3[base+2];
            }
            #pragma unroll
            for (int h = 0; h < 2; ++h) {
                int ks = a*8 + w + h*4;
                short8 afrag[4];
                #pragma unroll
                for (int mt = 0; mt < 4; ++mt) {
                    float dx = A[mt][0] - S[mt][h][0];
                    float dy = A[mt][1] - S[mt][h][1];
                    float dz = A[mt][2] - S[mt][h][2];
                    float d  = __builtin_amdgcn_sqrtf(fmaf(dz,dz,fmaf(dy,dy,fmaf(dx,dx,1e-6f))));
                    float u  = fmaf(d, 0.4f, -0.8f);
                    float e0 = __expf(-u*u) * am[mt][h];
                    float g  = __expf(fmaf(2.0f*DS, u, -DS*DS));
                    float fv[8];
                    fv[0] = e0;
                    #pragma unroll
                    for (int r = 1; r < 8; ++r) { e0 *= g; g *= QS; fv[r] = e0; }
                    afrag[mt] = pack8(fv);
                }
                #pragma unroll
                for (int nt = 0; nt < 8; ++nt) {
                    short8 b = bp[(nt*40 + ks)*64 + lane];
                    acc[0][nt] = __builtin_amdgcn_mfma_f32_16x16x32_bf16(afrag[0], b, acc[0][nt], 0,0,0);
                    acc[1][nt] = __builtin_amdgcn_mfma_f32_16x16x32_bf16(afrag[1], b, acc[1][nt], 0,0,0);
                    acc[2][nt] = __builtin_amdgcn_mfma_f32_16x16x32_bf16(afrag[2], b, acc[2][nt], 0,0,0);
                    acc[3][nt] = __builtin_amdgcn_mfma_f32_16x16x32_bf16(afrag[3], b, acc[3][nt], 0,0,0);
                }
            }
        }
        kred_ln<4>(acc, hb, out + OUT_ES + (size_t)id0*128, gs, bs, t, w, quad, l16);
    } else {
        // =============== edgeE: 416 -> 128 matvec + LN ===============
        // Scratch aliased inside hb: sdist/sposf are read through the K-loop,
        // which all waves finish before kred_ln's first barrier overwrites hb.
        float* sdist = hb;                     // 1728 (64 x 27): [0]=Dnb, [1+p]
        float* sposf = hb + 1728;              // 1088 (64 x 17)
        int*   sdpos = (int*)(hb + 2816);      // 64
        float* sA    = hb + 2880;              // 960 (64 x 15, dead after precompute)
        float* sB    = hb + 3840;              // 960 (64 x 15, dead after precompute)
        int id0 = (blockIdx.x - 768) * 64;

        if (t < 64) {
            int id = id0 + t, i = id / TOPK, j = Eidx[id];
            int off = ri[i] - ri[j];
            sdpos[t] = (ch[i] == ch[j]) ? min(max(off + 32, 0), 64) : 65;
            sdist[t*27] = Dnb[id];
        }
        for (int it = t; it < 64*15; it += 256) {
            int e = it / 15, q = it % 15;
            int id = id0 + e, i = id / TOPK, j = Eidx[id];
            sA[e*15+q] = coords[i*15+q];
            sB[e*15+q] = coords[j*15+q];
        }
        __syncthreads();
        for (int it = t; it < 64*24; it += 256) {
            int e = it / 24, p = it % 24, a = PA[p], b = PB[p];
            float dx = sA[e*15+a*3+0] - sB[e*15+b*3+0];
            float dy = sA[e*15+a*3+1] - sB[e*15+b*3+1];
            float dz = sA[e*15+a*3+2] - sB[e*15+b*3+2];
            sdist[e*27 + 1 + p] = __builtin_amdgcn_sqrtf(dx*dx + dy*dy + dz*dz + 1e-6f);
        }
        for (int it = t; it < 64*16; it += 256) {
            int e = it >> 4, c = it & 15;
            sposf[e*17 + c] = Wpos[c*66 + sdpos[e]] + bpos[c];
        }
        __syncthreads();

        f32x4 acc[4][8] = {};
        const short8* bp = (const short8*)WpE;
        float rb = (quad & 1) ? 8.0f*DE : 0.0f;

        for (int ks = w; ks < 13; ks += 4) {
            short8 afrag[4];
            #pragma unroll
            for (int mt = 0; mt < 4; ++mt) {
                int e = mt*16 + l16;
                float fv[8];
                if (ks == 0 && quad < 2) {
                    #pragma unroll
                    for (int j = 0; j < 8; ++j) fv[j] = sposf[e*17 + quad*8 + j];
                } else {
                    int p = (ks == 0) ? 0 : (2*ks - 1 + (quad >> 1));
                    float d = sdist[e*27 + p];
                    float u = fmaf(d, 0.8f, -1.6f) - rb;
                    float e0 = __expf(-u*u);
                    float g  = __expf(fmaf(2.0f*DE, u, -DE*DE));
                    fv[0] = e0;
                    #pragma unroll
                    for (int r = 1; r < 8; ++r) { e0 *= g; g *= QE; fv[r] = e0; }
                }
                afrag[mt] = pack8(fv);
            }
            #pragma unroll
            for (int nt = 0; nt < 8; ++nt) {
                short8 b = bp[(nt*13 + ks)*64 + lane];
                acc[0][nt] = __builtin_amdgcn_mfma_f32_16x16x32_bf16(afrag[0], b, acc[0][nt], 0,0,0);
                acc[1][nt] = __builtin_amdgcn_mfma_f32_16x16x32_bf16(afrag[1], b, acc[1][nt], 0,0,0);
                acc[2][nt] = __builtin_amdgcn_mfma_f32_16x16x32_bf16(afrag[2], b, acc[2][nt], 0,0,0);
                acc[3][nt] = __builtin_amdgcn_mfma_f32_16x16x32_bf16(afrag[3], b, acc[3][nt], 0,0,0);
            }
        }
        kred_ln<4>(acc, hb, out + OUT_E + (size_t)id0*128, ge, be, t, w, quad, l16);
    }
}

extern "C" void kernel_launch(void* const* d_in, const int* in_sizes, int n_in,
                              void* d_out, int out_size, void* d_ws, size_t ws_size,
                              hipStream_t stream) {
    (void)in_sizes; (void)n_in; (void)out_size; (void)ws_size;
    const float* X     = (const float*)d_in[0];
    const float* mask  = (const float*)d_in[2];
    const float* amask = (const float*)d_in[3];
    const int*   ri    = (const int*)d_in[4];
    const int*   ch    = (const int*)d_in[6];
    const float* Wpos  = (const float*)d_in[7];
    const float* bpos  = (const float*)d_in[8];
    const float* We    = (const float*)d_in[9];
    const float* ge    = (const float*)d_in[10];
    const float* be    = (const float*)d_in[11];
    const float* Ws    = (const float*)d_in[12];
    const float* gs    = (const float*)d_in[13];
    const float* bs    = (const float*)d_in[14];

    float* out    = (float*)d_out;
    float* ws     = (float*)d_ws;
    float* coords = ws + WS_COORDS;
    float* Dnb    = ws + WS_DNB;
    int*   Eidx   = (int*)(ws + WS_EIDX);
    short* WpE    = (short*)(ws + WS_WPE);
    short* WpS    = (short*)(ws + WS_WPS);

    k_pre <<<dim3(900),  dim3(256), 0, stream>>>(X, mask, We, Ws, coords,
                                                 WpE, WpS, Dnb, Eidx, out);
    k_edge<<<dim3(1536), dim3(256), 0, stream>>>(coords, X, amask, WpE, WpS,
                                                 Dnb, Eidx, ri, ch, Wpos, bpos,
                                                 ge, be, gs, bs, out);
}